// Round 4
// baseline (434.704 us; speedup 1.0000x reference)
//
#include <hip/hip_runtime.h>
#include <hip/hip_cooperative_groups.h>
#include <cstdint>

namespace cg = cooperative_groups;

#define HH 3000
#define WW 3000
#define WPR 48                    // 64-bit words per row (padded)
#define NW (HH * WPR)             // 144,000
#define TPB 256
#define NBLOCKS 1024
#define XBLK 12                   // 12 x-blocks of 256 columns per row
#define NVB (XBLK * HH)           // 36,000 virtual emit blocks

typedef unsigned long long u64;

// ws layout (every byte written before read):
//   +0        u64 bits[NW]        1,152,000 B
//   +1168384  int rowSums[3000]
//   +1184768  int P[NW]           576,000 B
#define BITS_OFF 0
#define ROWS_OFF 1168384
#define P_OFF    1184768

__global__ __launch_bounds__(TPB, 4) void k_fused(const void* __restrict__ acts,
                                                  const float* __restrict__ wts,
                                                  float* __restrict__ out,
                                                  int N, char* __restrict__ ws) {
    u64* bits    = (u64*)(ws + BITS_OFF);
    int* rowSums = (int*)(ws + ROWS_OFF);
    int* P       = (int*)(ws + P_OFF);

    const int b = blockIdx.x;
    const int t = threadIdx.x;
    const int lane = t & 63;
    const int wv = t >> 6;

    cg::grid_group grid = cg::this_grid();

    __shared__ int s_mode;
    __shared__ int s_red[4];
    __shared__ float4 s_vals[4][64];
    __shared__ float4 s_indA[4][64];
    __shared__ float4 s_indB[4][64];

    // ---- mode detect from first 256 words (L2 broadcast) ----
    // int32 bools -> words in {0,1}; byte bools -> words <= 0x01010101 (>1);
    // float bools -> words in {0, 0x3F800000} (> 0x01010101).
    {
        int v = (int)((const unsigned*)acts)[t];
        #pragma unroll
        for (int off = 32; off > 0; off >>= 1) v = max(v, __shfl_down(v, off));
        if (lane == 0) s_red[wv] = v;
        __syncthreads();
        if (t == 0) {
            int mx = max(max(s_red[0], s_red[1]), max(s_red[2], s_red[3]));
            s_mode = (mx > 1 && mx <= 0x01010101) ? 1 : 0;
        }
        __syncthreads();
    }
    const int mode = s_mode;

    // ---- phase 1: build bitmask + row sums (blocks 0..999, 3 rows each) ----
    if (b < 1000) {
        for (int rr = 0; rr < 3; ++rr) {
            int r = b * 3 + rr;
            long rowbase = (long)r * WW;
            int rcnt = 0;
            for (int it = 0; it < 12; ++it) {
                int wi = it * 4 + wv;            // 0..47
                int j = wi * 64 + lane;
                bool a = false;
                if (j < WW) {
                    if (mode) a = ((const unsigned char*)acts)[rowbase + j] != 0;
                    else      a = ((const unsigned*)acts)[rowbase + j] != 0u;
                }
                u64 m = __ballot(a);
                if (lane == 0) {
                    bits[r * WPR + wi] = m;
                    rcnt += __popcll(m);
                }
            }
            if (lane == 0) s_red[wv] = rcnt;
            __syncthreads();
            if (t == 0) rowSums[r] = s_red[0] + s_red[1] + s_red[2] + s_red[3];
            __syncthreads();
        }
    }
    grid.sync();

    // ---- phase 2: per-word absolute prefix P (redundant row-base reduction) ----
    if (b < 1000) {
        int r0 = b * 3;
        int s = 0;
        for (int idx = t; idx < r0; idx += TPB) s += rowSums[idx];
        #pragma unroll
        for (int off = 32; off > 0; off >>= 1) s += __shfl_down(s, off);
        if (lane == 0) s_red[wv] = s;
        __syncthreads();
        int base = s_red[0] + s_red[1] + s_red[2] + s_red[3];
        if (wv < 3) {
            int r = r0 + wv;
            int rbase = base;
            if (wv >= 1) rbase += rowSums[r0];
            if (wv >= 2) rbase += rowSums[r0 + 1];
            int w = r * WPR + lane;
            int v = (lane < WPR) ? __popcll(bits[w]) : 0;
            int x = v;
            #pragma unroll
            for (int off = 1; off < 64; off <<= 1) {
                int y = __shfl_up(x, off);
                if (lane >= off) x += y;
            }
            if (lane < WPR) P[w] = rbase + (x - v);
        }
    }
    grid.sync();

    // ---- phase 3: emit (grid-stride over 36,000 virtual blocks, barrier-free) ----
    float4* valsg = (float4*)out;                     // N float4
    float4* indsg = (float4*)(out + (size_t)N * 4);   // 2N float4
    for (int vb = b; vb < NVB; vb += NBLOCKS) {
        int i  = vb / XBLK;
        int bx = vb - i * XBLK;
        int j0 = bx * 256 + t;
        bool inrow = (j0 < WW);
        int j = inrow ? j0 : (WW - 1);
        int wi = j >> 6, bit = j & 63;
        int w = i * WPR + wi;
        u64 mself = bits[w];
        bool cellact = (mself >> bit) & 1ull;
        int v = P[w] + __popcll(mself & ((1ull << bit) - 1ull));
        bool act = inrow && cellact;
        if (!inrow && cellact) v += 1;     // keep v monotonic past row end

        int n0 = __shfl(v, 0);
        int a  = __shfl(v + (act ? 1 : 0), 63) - n0;

        if (act) {
            float nf = (float)v;
            const long c = (long)i * WW + j;
            float val[4], sf[4], tf[4];
            { // (1,0) down
                bool ok = (i < HH - 1);
                u64 wd = ok ? bits[w + WPR] : 0ull;
                bool aa = ok && ((wd >> bit) & 1ull);
                val[0] = aa ? wts[c + WW] : 0.f; sf[0] = aa ? nf : 0.f;
                tf[0] = aa ? (float)(P[w + WPR] + __popcll(wd & ((1ull << bit) - 1ull))) : 0.f;
            }
            { // (-1,0) up
                bool ok = (i > 0);
                u64 wd = ok ? bits[w - WPR] : 0ull;
                bool aa = ok && ((wd >> bit) & 1ull);
                val[1] = aa ? wts[c - WW] : 0.f; sf[1] = aa ? nf : 0.f;
                tf[1] = aa ? (float)(P[w - WPR] + __popcll(wd & ((1ull << bit) - 1ull))) : 0.f;
            }
            { // (0,1) right
                bool ok = (j < WW - 1);
                int wn = (bit < 63) ? w : w + 1;
                int b2 = (bit < 63) ? bit + 1 : 0;
                u64 wd = ok ? ((bit < 63) ? mself : bits[wn]) : 0ull;
                bool aa = ok && ((wd >> b2) & 1ull);
                val[2] = aa ? wts[c + 1] : 0.f; sf[2] = aa ? nf : 0.f;
                tf[2] = aa ? (float)(P[wn] + __popcll(wd & ((1ull << b2) - 1ull))) : 0.f;
            }
            { // (0,-1) left
                bool ok = (j > 0);
                int wn = (bit > 0) ? w : w - 1;
                int b2 = (bit > 0) ? bit - 1 : 63;
                u64 wd = ok ? ((bit > 0) ? mself : bits[wn]) : 0ull;
                bool aa = ok && ((wd >> b2) & 1ull);
                val[3] = aa ? wts[c - 1] : 0.f; sf[3] = aa ? nf : 0.f;
                tf[3] = aa ? (float)(P[wn] + __popcll(wd & ((1ull << b2) - 1ull))) : 0.f;
            }
            int rloc = v - n0;
            s_vals[wv][rloc] = make_float4(val[0], val[1], val[2], val[3]);
            s_indA[wv][rloc] = make_float4(sf[0], tf[0], sf[1], tf[1]);
            s_indB[wv][rloc] = make_float4(sf[2], tf[2], sf[3], tf[3]);
        }
        // per-wave LDS staging: same-wave write->read, no block barrier needed
        if (lane < a) valsg[(size_t)n0 + lane] = s_vals[wv][lane];
        int twoa = 2 * a;
        if (lane < twoa)
            indsg[2 * (size_t)n0 + lane] =
                (lane & 1) ? s_indB[wv][lane >> 1] : s_indA[wv][lane >> 1];
        int k2 = lane + 64;
        if (k2 < twoa)
            indsg[2 * (size_t)n0 + k2] =
                (k2 & 1) ? s_indB[wv][k2 >> 1] : s_indA[wv][k2 >> 1];
    }
}

extern "C" void kernel_launch(void* const* d_in, const int* in_sizes, int n_in,
                              void* d_out, int out_size, void* d_ws, size_t ws_size,
                              hipStream_t stream) {
    const void* acts = d_in[0];
    const float* wts = (const float*)d_in[1];
    float* out = (float*)d_out;
    int N = out_size / 12;
    char* ws = (char*)d_ws;

    void* args[] = {(void*)&acts, (void*)&wts, (void*)&out, (void*)&N, (void*)&ws};
    hipLaunchCooperativeKernel((void*)k_fused, dim3(NBLOCKS), dim3(TPB), args, 0, stream);
}

// Round 5
// 107.784 us; speedup vs baseline: 4.0331x; 4.0331x over previous
//
#include <hip/hip_runtime.h>
#include <cstdint>

#define HH 3000
#define WW 3000
#define WPR 48                    // 64-bit words per row (3000 bits, padded)
#define NW (HH * WPR)             // 144,000

typedef unsigned long long u64;
typedef float f4v __attribute__((ext_vector_type(4)));

// ws layout (every byte written before read):
//   +0        u64 bits[NW]        1,152,000 B
//   +1152000  int rowSums[3000]
//   +1164032  int P[NW]           576,000 B
#define BITS_OFF 0
#define ROWS_OFF 1152000
#define P_OFF    1164032

__device__ __forceinline__ void nt_store4(const float4& v, float4* p) {
    f4v x; x.x = v.x; x.y = v.y; x.z = v.z; x.w = v.w;
    __builtin_nontemporal_store(x, (f4v*)p);
}

// Inline layout detection from the first 256 words (1 KB, L2-broadcast):
// int32 bools -> words in {0,1}; byte bools -> words in [0,0x01010101];
// float bools -> words in {0,0x3F800000}.
__device__ __forceinline__ int detect_mode(const void* acts, int t, int lane, int wv,
                                           int* s_red, int* s_mode) {
    int v = (int)((const unsigned*)acts)[t];
    #pragma unroll
    for (int off = 32; off > 0; off >>= 1) v = max(v, __shfl_down(v, off));
    if (lane == 0) s_red[wv] = v;
    __syncthreads();
    if (t == 0) {
        int mx = max(max(s_red[0], s_red[1]), max(s_red[2], s_red[3]));
        *s_mode = (mx > 1 && mx <= 0x01010101) ? 1 : 0;
    }
    __syncthreads();
    return *s_mode;
}

// ---- build: one block per row; ballot-packed bitmask + row sum ----
__global__ __launch_bounds__(256) void k_build(const void* __restrict__ acts,
                                               u64* __restrict__ bits,
                                               int* __restrict__ rowSums) {
    __shared__ int s_red[4];
    __shared__ int s_mode;
    const int t = threadIdx.x, lane = t & 63, wv = t >> 6;
    const int mode = detect_mode(acts, t, lane, wv, s_red, &s_mode);

    const int r = blockIdx.x;
    const long rowbase = (long)r * WW;
    int mycnt = 0;
    for (int it = 0; it < 12; ++it) {
        int wi = it * 4 + wv;            // 0..47
        int j = wi * 64 + lane;
        bool a = false;
        if (j < WW) {
            if (mode) a = ((const unsigned char*)acts)[rowbase + j] != 0;
            else      a = ((const unsigned*)acts)[rowbase + j] != 0u;
        }
        u64 m = __ballot(a);
        if (lane == 0) {
            bits[r * WPR + wi] = m;
            mycnt += __popcll(m);
        }
    }
    if (lane == 0) s_red[wv] = mycnt;
    __syncthreads();
    if (t == 0) rowSums[r] = s_red[0] + s_red[1] + s_red[2] + s_red[3];
}

// ---- prefix: 4 rows per block; redundant base reduction + wave scan per row ----
__global__ __launch_bounds__(256) void k_prefixP(const u64* __restrict__ bits,
                                                 const int* __restrict__ rowSums,
                                                 int* __restrict__ P) {
    __shared__ int s_red[4];
    const int t = threadIdx.x, lane = t & 63, wv = t >> 6;
    const int r0 = blockIdx.x * 4;
    // exclusive base = sum rowSums[0..r0)
    int s = 0;
    for (int idx = t; idx < r0; idx += 256) s += rowSums[idx];
    #pragma unroll
    for (int off = 32; off > 0; off >>= 1) s += __shfl_down(s, off);
    if (lane == 0) s_red[wv] = s;
    __syncthreads();
    int base = s_red[0] + s_red[1] + s_red[2] + s_red[3];

    const int r = r0 + wv;
    if (r < HH) {
        int rbase = base;
        if (wv >= 1) rbase += rowSums[r0];
        if (wv >= 2) rbase += rowSums[r0 + 1];
        if (wv >= 3) rbase += rowSums[r0 + 2];
        const int w = r * WPR + lane;
        int v = (lane < WPR) ? __popcll(bits[w]) : 0;
        int x = v;
        #pragma unroll
        for (int off = 1; off < 64; off <<= 1) {
            int y = __shfl_up(x, off);
            if (lane >= off) x += y;
        }
        if (lane < WPR) P[w] = rbase + (x - v);  // absolute exclusive prefix
    }
}

// ---- emit: grid (12, 3000); per-wave LDS staging, coalesced nt wave stores ----
__global__ __launch_bounds__(256) void k_emit(const u64* __restrict__ bits,
                                              const int* __restrict__ P,
                                              const float* __restrict__ wts,
                                              float* __restrict__ out, int N) {
    const int t = threadIdx.x;
    const int lane = t & 63;
    const int wv = t >> 6;
    const int i = blockIdx.y;
    const int j0 = blockIdx.x * 256 + t;

    __shared__ float4 s_vals[4][64];
    __shared__ float4 s_inds[4][128];

    bool inrow = (j0 < WW);
    int j = inrow ? j0 : (WW - 1);
    int wi = j >> 6, bit = j & 63;
    int w = i * WPR + wi;
    u64 mself = bits[w];
    bool cellact = (mself >> bit) & 1ull;
    int v = P[w] + __popcll(mself & ((1ull << bit) - 1ull));  // virtual rank
    bool act = inrow && cellact;
    if (!inrow && cellact) v += 1;   // keep v monotonic past row end

    int n0 = __shfl(v, 0);                       // wave base rank
    int a  = __shfl(v + (act ? 1 : 0), 63) - n0; // active lanes in wave

    if (act) {
        float nf = (float)v;
        const long c = (long)i * WW + j;
        float val[4], sf[4], tf[4];
        { // (1,0) down
            bool ok = (i < HH - 1);
            u64 wd = ok ? bits[w + WPR] : 0ull;
            bool aa = ok && ((wd >> bit) & 1ull);
            val[0] = aa ? wts[c + WW] : 0.f; sf[0] = aa ? nf : 0.f;
            tf[0] = aa ? (float)(P[w + WPR] + __popcll(wd & ((1ull << bit) - 1ull))) : 0.f;
        }
        { // (-1,0) up
            bool ok = (i > 0);
            u64 wd = ok ? bits[w - WPR] : 0ull;
            bool aa = ok && ((wd >> bit) & 1ull);
            val[1] = aa ? wts[c - WW] : 0.f; sf[1] = aa ? nf : 0.f;
            tf[1] = aa ? (float)(P[w - WPR] + __popcll(wd & ((1ull << bit) - 1ull))) : 0.f;
        }
        { // (0,1) right
            bool ok = (j < WW - 1);
            int wn = (bit < 63) ? w : w + 1;
            int b2 = (bit < 63) ? bit + 1 : 0;
            u64 wd = ok ? ((bit < 63) ? mself : bits[wn]) : 0ull;
            bool aa = ok && ((wd >> b2) & 1ull);
            val[2] = aa ? wts[c + 1] : 0.f; sf[2] = aa ? nf : 0.f;
            tf[2] = aa ? (float)(P[wn] + __popcll(wd & ((1ull << b2) - 1ull))) : 0.f;
        }
        { // (0,-1) left
            bool ok = (j > 0);
            int wn = (bit > 0) ? w : w - 1;
            int b2 = (bit > 0) ? bit - 1 : 63;
            u64 wd = ok ? ((bit > 0) ? mself : bits[wn]) : 0ull;
            bool aa = ok && ((wd >> b2) & 1ull);
            val[3] = aa ? wts[c - 1] : 0.f; sf[3] = aa ? nf : 0.f;
            tf[3] = aa ? (float)(P[wn] + __popcll(wd & ((1ull << b2) - 1ull))) : 0.f;
        }
        int rloc = v - n0;
        s_vals[wv][rloc]         = make_float4(val[0], val[1], val[2], val[3]);
        s_inds[wv][2 * rloc]     = make_float4(sf[0], tf[0], sf[1], tf[1]);
        s_inds[wv][2 * rloc + 1] = make_float4(sf[2], tf[2], sf[3], tf[3]);
    }
    // per-wave staging: DS ops are wave-ordered, no block barrier needed
    float4* valsg = (float4*)out;                     // N float4s
    float4* indsg = (float4*)(out + (size_t)N * 4);   // 2N float4s
    if (lane < a) nt_store4(s_vals[wv][lane], &valsg[(size_t)n0 + lane]);
    int twoa = 2 * a;
    if (lane < twoa)      nt_store4(s_inds[wv][lane],      &indsg[2 * (size_t)n0 + lane]);
    if (lane + 64 < twoa) nt_store4(s_inds[wv][lane + 64], &indsg[2 * (size_t)n0 + 64 + lane]);
}

extern "C" void kernel_launch(void* const* d_in, const int* in_sizes, int n_in,
                              void* d_out, int out_size, void* d_ws, size_t ws_size,
                              hipStream_t stream) {
    const void* acts = d_in[0];
    const float* wts = (const float*)d_in[1];
    float* out = (float*)d_out;
    const int N = out_size / 12;

    u64* bits = (u64*)((char*)d_ws + BITS_OFF);
    int* rows = (int*)((char*)d_ws + ROWS_OFF);
    int* P    = (int*)((char*)d_ws + P_OFF);

    k_build<<<HH, 256, 0, stream>>>(acts, bits, rows);
    k_prefixP<<<(HH + 3) / 4, 256, 0, stream>>>(bits, rows, P);
    k_emit<<<dim3(12, HH), 256, 0, stream>>>(bits, P, wts, out, N);
}